// Round 10
// baseline (646.987 us; speedup 1.0000x reference)
//
#include <hip/hip_runtime.h>
#include <hip/hip_bf16.h>

// ---------------------------------------------------------------------------
// GINE 2-layer GNN, MI355X (gfx950)  — round 10 (R9 design, compile fix:
// HIP predefines `short4`; renamed our 4-elem bf16 vector to bhalf4)
//
// R8 post-mortem: edge2 ran 5x over its roofline on per-wave serial
// overhead (LDS transpose round-trip, 96 f2bf, 32 ds_write_b16, occ cap).
// Fix: OPERAND-SWAPPED edge GEMM. Compute ea^T = We @ eattr^T:
//   A-frag = We rows ([f][k] = WeB's native layout)
//   B-frag = eattr[edge c][k]  (identical loads to the old A-frags)
//   C: lane (g,c) holds m[edge c][f = fc*16+g*4+r] -> 4 CONTIGUOUS feats
//   of ONE edge: x-add = one 8B bf16 load, store = one 8B store. No LDS.
// GEMM2 eliminated via linearity (both layers): store full m per edge,
// aggregate s = x + sum(m) streaming, then node-tile MFMA applies W1.
// ---------------------------------------------------------------------------

typedef short bhalf4 __attribute__((ext_vector_type(4)));
typedef short short8 __attribute__((ext_vector_type(8)));
typedef float f32x4 __attribute__((ext_vector_type(4)));
typedef float f32x2 __attribute__((ext_vector_type(2)));

__device__ __forceinline__ short f2bf(float x) {
    unsigned u = __float_as_uint(x);
    unsigned r = (u + 0x7fffu + ((u >> 16) & 1u)) >> 16;   // RTNE
    return (short)r;
}
__device__ __forceinline__ float bf2f(unsigned short u) {
    return __uint_as_float(((unsigned)u) << 16);
}

// ---------------------------------------------------------------------------
// Counting sort of edges by dst -> inv (edge id -> sorted pos), offs (CSR)
// ---------------------------------------------------------------------------
__global__ __launch_bounds__(256) void hist_kernel(
    const int* __restrict__ ei, int* __restrict__ cnt, int E)
{
    int e = blockIdx.x * 256 + threadIdx.x;
    if (e < E) atomicAdd(&cnt[ei[E + e]], 1);
}

__global__ __launch_bounds__(1024) void scan_kernel(
    const int* __restrict__ cnt, int* __restrict__ offs,
    int* __restrict__ cursor, int N)
{
    __shared__ int wsum[16];
    __shared__ int chunk_base;
    int tid = threadIdx.x;
    int lane = tid & 63, wid = tid >> 6;
    if (tid == 0) chunk_base = 0;
    __syncthreads();
    for (int start = 0; start < N; start += 1024) {
        int i = start + tid;
        int v = (i < N) ? cnt[i] : 0;
        int s = v;
#pragma unroll
        for (int d = 1; d < 64; d <<= 1) {
            int t = __shfl_up(s, d);
            if (lane >= d) s += t;
        }
        if (lane == 63) wsum[wid] = s;
        __syncthreads();
        int wbase = 0;
        for (int w = 0; w < wid; ++w) wbase += wsum[w];
        int excl = chunk_base + wbase + s - v;
        if (i < N) { offs[i] = excl; cursor[i] = excl; }
        int tot = 0;
        for (int w = 0; w < 16; ++w) tot += wsum[w];
        __syncthreads();
        if (tid == 0) chunk_base += tot;
        __syncthreads();
    }
    if (threadIdx.x == 0) offs[N] = chunk_base;
}

__global__ __launch_bounds__(256) void scatter_kernel(
    const int* __restrict__ ei, int* __restrict__ cursor,
    int* __restrict__ inv, int E)
{
    int e = blockIdx.x * 256 + threadIdx.x;
    if (e >= E) return;
    int d = ei[E + e];
    int pos = atomicAdd(&cursor[d], 1);
    inv[e] = pos;
}

// ---------------------------------------------------------------------------
// x -> bf16 cast (grid-stride)
// ---------------------------------------------------------------------------
__global__ __launch_bounds__(256) void xcast_kernel(
    const float* __restrict__ x, unsigned short* __restrict__ xb, int total)
{
    for (int i = blockIdx.x * 256 + threadIdx.x; i < total; i += gridDim.x * 256)
        xb[i] = (unsigned short)f2bf(x[i]);
}

// ---------------------------------------------------------------------------
// Edge kernel (swapped operands, no LDS, no GEMM2). DF = 128 (L0) / 64 (L1).
//   m[e][f] = relu( (eattr @ We^T)[e][f] + be[f] + x[src(e)][f] )
// Wave = 16 edges. A = We [DF f][64 k]; B = eattr^T (lane c holds edge c's
// k-slice). C: lane (g,c) -> m[edge c][fc*16 + g*4 + r], r=0..3.
// Store 8B per chunk at dst-sorted row inv[e].
// ---------------------------------------------------------------------------
template<int DF>
__global__ __launch_bounds__(256) void edgem_kernel(
    const unsigned short* __restrict__ xb,   // [N][DF] bf16 node feats
    const int*    __restrict__ ei,           // [2][E] (src used)
    const float*  __restrict__ eattr,        // [E][64]
    const short*  __restrict__ WB,           // [DF][64] bf16 (We native)
    const float*  __restrict__ be,           // [DF]
    const int*    __restrict__ inv,          // [E] edge -> sorted pos
    unsigned short* __restrict__ pbuf,       // [E][DF] bf16 (sorted rows)
    int E)
{
    constexpr int FC = DF / 16;
    const int wave = threadIdx.x >> 6;
    const int lane = threadIdx.x & 63;
    const int ebase = (blockIdx.x * 4 + wave) * 16;
    if (ebase >= E) return;
    const int g = lane >> 4, c = lane & 15;

    // ---- load burst: this lane's edge (c), its src row slices, eattr ----
    int ce = ebase + c;
    bool cv = ce < E;
    int ces = cv ? ce : (E - 1);
    int se = ei[ces];
    int sp = cv ? inv[ces] : -1;

    const float* ar = eattr + (size_t)ces * 64 + g * 8;
    f32x4 a0 = *(const f32x4*)(ar);
    f32x4 a1 = *(const f32x4*)(ar + 4);
    f32x4 a2 = *(const f32x4*)(ar + 32);
    f32x4 a3 = *(const f32x4*)(ar + 36);

    // x slices: lane (g,c) needs x[se][fc*16 + g*4 .. +3] (8B each)
    bhalf4 xv[FC];
    const unsigned short* xr = xb + (size_t)se * DF + g * 4;
#pragma unroll
    for (int fc = 0; fc < FC; ++fc)
        xv[fc] = *(const bhalf4*)(xr + fc * 16);
    __builtin_amdgcn_sched_barrier(0);   // keep the burst up here

    // ---- B-frags (eattr -> bf16), k-tiles {0..31},{32..63} ----
    short8 bfr0, bfr1;
    bfr0[0]=f2bf(a0[0]); bfr0[1]=f2bf(a0[1]); bfr0[2]=f2bf(a0[2]); bfr0[3]=f2bf(a0[3]);
    bfr0[4]=f2bf(a1[0]); bfr0[5]=f2bf(a1[1]); bfr0[6]=f2bf(a1[2]); bfr0[7]=f2bf(a1[3]);
    bfr1[0]=f2bf(a2[0]); bfr1[1]=f2bf(a2[1]); bfr1[2]=f2bf(a2[2]); bfr1[3]=f2bf(a2[3]);
    bfr1[4]=f2bf(a3[0]); bfr1[5]=f2bf(a3[1]); bfr1[6]=f2bf(a3[2]); bfr1[7]=f2bf(a3[3]);

    // ---- per f-chunk: 2 MFMA + epilogue + 8B store ----
#pragma unroll
    for (int fc = 0; fc < FC; ++fc) {
        const short* aw = WB + (size_t)(fc * 16 + c) * 64 + g * 8;
        short8 aw0 = *(const short8*)(aw);
        short8 aw1 = *(const short8*)(aw + 32);
        f32x4 acc = {0.f, 0.f, 0.f, 0.f};
        acc = __builtin_amdgcn_mfma_f32_16x16x32_bf16(aw0, bfr0, acc, 0, 0, 0);
        acc = __builtin_amdgcn_mfma_f32_16x16x32_bf16(aw1, bfr1, acc, 0, 0, 0);

        f32x4 bev = *(const f32x4*)(be + fc * 16 + g * 4);
        bhalf4 outp;
#pragma unroll
        for (int r = 0; r < 4; ++r) {
            float v = acc[r] + bev[r] + bf2f((unsigned short)xv[fc][r]);
            outp[r] = f2bf(fmaxf(v, 0.f));
        }
        if (sp >= 0)
            *(bhalf4*)(pbuf + (size_t)sp * DF + fc * 16 + g * 4) = outp;
    }
}

// ---------------------------------------------------------------------------
// L0 gather-sum (streaming, DF=128): sb[n][k] = bf16(x[n][k] + sum_i pbuf[i][k])
// Wave per node; lane owns 2 feats (one dword of pbuf).
// ---------------------------------------------------------------------------
__global__ __launch_bounds__(256) void gathersum0_kernel(
    const unsigned short* __restrict__ pbuf,   // [E][128] sorted rows
    const int* __restrict__ offs,
    const float* __restrict__ x,               // [N][128] f32
    unsigned short* __restrict__ sb, int N)
{
    int wid = threadIdx.x >> 6, lane = threadIdx.x & 63;
    int n = blockIdx.x * 4 + wid;
    if (n >= N) return;
    f32x2 xx = *(const f32x2*)(x + (size_t)n * 128 + 2 * lane);
    float s0 = xx[0], s1 = xx[1];
    int i0 = offs[n], i1 = offs[n + 1];
    const unsigned int* p = (const unsigned int*)(pbuf + (size_t)i0 * 128) + lane;
    int cnt = i1 - i0;
    int i = 0;
    for (; i + 3 < cnt; i += 4) {
        unsigned int v0 = p[0], v1 = p[64], v2 = p[128], v3 = p[192];
        s0 += bf2f((unsigned short)v0) + bf2f((unsigned short)v1)
            + bf2f((unsigned short)v2) + bf2f((unsigned short)v3);
        s1 += bf2f((unsigned short)(v0 >> 16)) + bf2f((unsigned short)(v1 >> 16))
            + bf2f((unsigned short)(v2 >> 16)) + bf2f((unsigned short)(v3 >> 16));
        p += 256;
    }
    for (; i < cnt; ++i) {
        unsigned int v = p[0];
        s0 += bf2f((unsigned short)v);
        s1 += bf2f((unsigned short)(v >> 16));
        p += 64;
    }
    unsigned int packed = (unsigned int)(unsigned short)f2bf(s0)
                        | ((unsigned int)(unsigned short)f2bf(s1) << 16);
    *(unsigned int*)(sb + (size_t)n * 128 + 2 * lane) = packed;
}

// ---------------------------------------------------------------------------
// L1 gather-sum (streaming, DF=64): sb[n][k] = bf16(y0[n][k] + sum_i pbuf[i][k])
// ---------------------------------------------------------------------------
__global__ __launch_bounds__(256) void gathersum1_kernel(
    const unsigned short* __restrict__ pbuf,   // [E][64] sorted rows
    const int* __restrict__ offs,
    const float* __restrict__ y0, unsigned short* __restrict__ sb, int N)
{
    int wid = threadIdx.x >> 6, lane = threadIdx.x & 63;
    int n = blockIdx.x * 4 + wid;
    if (n >= N) return;
    float s = y0[(size_t)n * 64 + lane];
    int i0 = offs[n], i1 = offs[n + 1];
    const unsigned short* p = pbuf + (size_t)i0 * 64 + lane;
    int cnt = i1 - i0;
    int i = 0;
    for (; i + 3 < cnt; i += 4) {
        s += bf2f(p[0]) + bf2f(p[64]) + bf2f(p[128]) + bf2f(p[192]);
        p += 256;
    }
    for (; i < cnt; ++i) { s += bf2f(p[0]); p += 64; }
    sb[(size_t)n * 64 + lane] = (unsigned short)f2bf(s);
}

// ---------------------------------------------------------------------------
// Node-tile MFMA GEMM: out[n][f] = b[f] + sum_k A[n][k] * W[f][k]
// ---------------------------------------------------------------------------
template<int DIN>
__global__ __launch_bounds__(256) void ngemm_kernel(
    const unsigned short* __restrict__ A,
    const short* __restrict__ W, const float* __restrict__ b,
    float* __restrict__ out, int N)
{
    constexpr int KK = DIN / 32;
    const int wave = threadIdx.x >> 6;
    const int lane = threadIdx.x & 63;
    const int nbase = (blockIdx.x * 4 + wave) * 16;
    if (nbase >= N) return;
    const int g = lane >> 4, c = lane & 15;

    int rowc = nbase + c; if (rowc >= N) rowc = N - 1;
    const unsigned short* arow = A + (size_t)rowc * DIN + g * 8;
    short8 afr[KK];
#pragma unroll
    for (int kk = 0; kk < KK; ++kk)
        afr[kk] = *(const short8*)(arow + kk * 32);

#pragma unroll
    for (int cc = 0; cc < 4; ++cc) {
        const float bev = b[cc * 16 + c];
        f32x4 acc = {bev, bev, bev, bev};
#pragma unroll
        for (int kk = 0; kk < KK; ++kk) {
            short8 bw = *(const short8*)(W + (size_t)(cc * 16 + c) * DIN + kk * 32 + g * 8);
            acc = __builtin_amdgcn_mfma_f32_16x16x32_bf16(afr[kk], bw, acc, 0, 0, 0);
        }
#pragma unroll
        for (int r = 0; r < 4; ++r) {
            int row = nbase + g * 4 + r;
            if (row < N) out[(size_t)row * 64 + cc * 16 + c] = acc[r];
        }
    }
}

// ---------------------------------------------------------------------------
// Node-tile MFMA GEMM with fused BN+relu on the A side
// ---------------------------------------------------------------------------
__global__ __launch_bounds__(256) void ngemm_bn_kernel(
    const float* __restrict__ t, const float* __restrict__ scsh,
    const short* __restrict__ W2, const float* __restrict__ b2,
    float* __restrict__ out, unsigned short* __restrict__ outb,
    int N, int relu_out)
{
    const int wave = threadIdx.x >> 6;
    const int lane = threadIdx.x & 63;
    const int nbase = (blockIdx.x * 4 + wave) * 16;
    if (nbase >= N) return;
    const int g = lane >> 4, c = lane & 15;

    int rowc = nbase + c; if (rowc >= N) rowc = N - 1;
    const float* trow = t + (size_t)rowc * 64 + g * 8;

    short8 afr[2];
#pragma unroll
    for (int kk = 0; kk < 2; ++kk) {
        f32x4 q0 = *(const f32x4*)(trow + kk * 32);
        f32x4 q1 = *(const f32x4*)(trow + kk * 32 + 4);
        const int kbase = kk * 32 + g * 8;
        f32x4 sc0 = *(const f32x4*)(scsh + kbase);
        f32x4 sc1 = *(const f32x4*)(scsh + kbase + 4);
        f32x4 sh0 = *(const f32x4*)(scsh + 64 + kbase);
        f32x4 sh1 = *(const f32x4*)(scsh + 64 + kbase + 4);
#pragma unroll
        for (int j = 0; j < 4; ++j) {
            afr[kk][j]     = f2bf(fmaxf(q0[j] * sc0[j] + sh0[j], 0.f));
            afr[kk][j + 4] = f2bf(fmaxf(q1[j] * sc1[j] + sh1[j], 0.f));
        }
    }

#pragma unroll
    for (int cc = 0; cc < 4; ++cc) {
        const float bev = b2[cc * 16 + c];
        f32x4 acc = {bev, bev, bev, bev};
#pragma unroll
        for (int kk = 0; kk < 2; ++kk) {
            short8 bw = *(const short8*)(W2 + (size_t)(cc * 16 + c) * 64 + kk * 32 + g * 8);
            acc = __builtin_amdgcn_mfma_f32_16x16x32_bf16(afr[kk], bw, acc, 0, 0, 0);
        }
#pragma unroll
        for (int r = 0; r < 4; ++r) {
            int row = nbase + g * 4 + r;
            if (row < N) {
                float v = acc[r];
                if (relu_out) {
                    v = fmaxf(v, 0.f);
                    outb[(size_t)row * 64 + cc * 16 + c] = (unsigned short)f2bf(v);
                }
                out[(size_t)row * 64 + cc * 16 + c] = v;
            }
        }
    }
}

// ---------------------------------------------------------------------------
// BN stats + final
// ---------------------------------------------------------------------------
__global__ __launch_bounds__(256) void bnstats_kernel(
    const float* __restrict__ t, float* __restrict__ sums, int total)
{
    int tid = threadIdx.x;
    float s = 0.f, s2 = 0.f;
    for (int i = blockIdx.x * 256 + tid; i < total; i += gridDim.x * 256) {
        float v = t[i];
        s += v; s2 += v * v;
    }
    __shared__ float ls[256], ls2[256];
    ls[tid] = s; ls2[tid] = s2;
    __syncthreads();
    if (tid < 64) {
        s  = ls[tid]  + ls[tid + 64]  + ls[tid + 128]  + ls[tid + 192];
        s2 = ls2[tid] + ls2[tid + 64] + ls2[tid + 128] + ls2[tid + 192];
        atomicAdd(&sums[tid], s);
        atomicAdd(&sums[64 + tid], s2);
    }
}

__global__ void bnfinal_kernel(const float* __restrict__ sums,
                               const float* __restrict__ g,
                               const float* __restrict__ bb,
                               float* __restrict__ scsh, float invN)
{
    int f = threadIdx.x;  // 64 threads
    float mean = sums[f] * invN;
    float var  = sums[64 + f] * invN - mean * mean;
    float sc = g[f] * rsqrtf(var + 1e-5f);
    scsh[f] = sc;
    scsh[64 + f] = bb[f] - mean * sc;
}

// ---------------------------------------------------------------------------
// Weight prep: f32 -> bf16
// ---------------------------------------------------------------------------
__global__ __launch_bounds__(256) void prep_kernel(
    const float* __restrict__ We0, const float* __restrict__ W1_0,
    const float* __restrict__ We1, const float* __restrict__ W1_1,
    const float* __restrict__ W2_0, const float* __restrict__ W2_1,
    short* __restrict__ WeB0, short* __restrict__ W1B0,
    short* __restrict__ WeB1, short* __restrict__ W1B1,
    short* __restrict__ W2B0, short* __restrict__ W2B1)
{
    int i = blockIdx.x * 256 + threadIdx.x;
    if (i < 128 * 64) WeB0[i] = f2bf(We0[i]);
    if (i < 64 * 128) W1B0[i] = f2bf(W1_0[i]);
    if (i < 64 * 64) {
        WeB1[i] = f2bf(We1[i]);
        W1B1[i] = f2bf(W1_1[i]);
        W2B0[i] = f2bf(W2_0[i]);
        W2B1[i] = f2bf(W2_1[i]);
    }
}

extern "C" void kernel_launch(void* const* d_in, const int* in_sizes, int n_in,
                              void* d_out, int out_size, void* d_ws, size_t ws_size,
                              hipStream_t stream)
{
    (void)n_in; (void)out_size; (void)ws_size;
    const float* x     = (const float*)d_in[0];
    const int*   ei    = (const int*)d_in[1];
    const float* eattr = (const float*)d_in[2];
    const float* We0   = (const float*)d_in[3];
    const float* be0   = (const float*)d_in[4];
    const float* W1_0  = (const float*)d_in[5];
    const float* b1_0  = (const float*)d_in[6];
    const float* g0    = (const float*)d_in[7];
    const float* bb0   = (const float*)d_in[8];
    const float* W2_0  = (const float*)d_in[9];
    const float* b2_0  = (const float*)d_in[10];
    const float* We1   = (const float*)d_in[11];
    const float* be1   = (const float*)d_in[12];
    const float* W1_1  = (const float*)d_in[13];
    const float* b1_1  = (const float*)d_in[14];
    const float* g1    = (const float*)d_in[15];
    const float* bb1   = (const float*)d_in[16];
    const float* W2_1  = (const float*)d_in[17];
    const float* b2_1  = (const float*)d_in[18];
    float* out = (float*)d_out;

    const int N = in_sizes[0] / 128;   // 50000
    const int E = in_sizes[2] / 64;    // 800000

    char* ws = (char*)d_ws;
    size_t o = 0;
    auto alloc = [&](size_t bytes) { char* p = ws + o; o = (o + bytes + 255) & ~(size_t)255; return p; };
    unsigned short* pbuf = (unsigned short*)alloc((size_t)E * 128 * 2);  // L0: [E][128]; L1 reuses as [E][64]
    float* tbuf   = (float*)alloc((size_t)N * 64 * 4);
    float* y0     = (float*)alloc((size_t)N * 64 * 4);
    unsigned short* xb = (unsigned short*)alloc((size_t)N * 128 * 2);   // also sb0 (after edge2)
    unsigned short* yb = (unsigned short*)alloc((size_t)N * 64 * 2);    // also sb1 (after edge1)
    short* WeB0   = (short*)alloc(128 * 64 * 2);
    short* W1B0   = (short*)alloc(64 * 128 * 2);
    short* WeB1   = (short*)alloc(64 * 64 * 2);
    short* W1B1   = (short*)alloc(64 * 64 * 2);
    short* W2B0   = (short*)alloc(64 * 64 * 2);
    short* W2B1   = (short*)alloc(64 * 64 * 2);
    float* stats  = (float*)alloc(512 * 4);
    int*   cnt    = (int*)alloc((size_t)N * 4);
    int*   offs   = (int*)alloc((size_t)(N + 1) * 4);
    int*   inv    = (int*)alloc((size_t)E * 4);
    float* sum0  = stats;
    float* scsh0 = stats + 128;
    float* sum1  = stats + 256;
    float* scsh1 = stats + 384;
    unsigned short* sb0 = xb;   // alias: written after edge2 consumed xb
    unsigned short* sb1 = yb;   // alias: written after edge1 consumed yb

    (void)hipMemsetAsync(stats, 0, 512 * 4, stream);
    (void)hipMemsetAsync(cnt, 0, (size_t)N * 4, stream);
    prep_kernel<<<64, 256, 0, stream>>>(We0, W1_0, We1, W1_1, W2_0, W2_1,
                                        WeB0, W1B0, WeB1, W1B1, W2B0, W2B1);
    xcast_kernel<<<2048, 256, 0, stream>>>(x, xb, N * 128);

    const int eb256 = (E + 255) / 256;

    // ----- CSR by dst (offs) + edge -> sorted-position map (inv) -----
    hist_kernel<<<eb256, 256, 0, stream>>>(ei, cnt, E);
    scan_kernel<<<1, 1024, 0, stream>>>(cnt, offs, cnt, N);
    scatter_kernel<<<eb256, 256, 0, stream>>>(ei, cnt, inv, E);

    const int edge_blocks = ((E + 15) / 16 + 3) / 4;
    const int n4_blocks   = (N + 3) / 4;
    const int nt_blocks   = ((N + 15) / 16 + 3) / 4;

    // ----- layer 0 -----
    edgem_kernel<128><<<edge_blocks, 256, 0, stream>>>(
        xb, ei, eattr, WeB0, be0, inv, pbuf, E);
    gathersum0_kernel<<<n4_blocks, 256, 0, stream>>>(pbuf, offs, x, sb0, N);
    ngemm_kernel<128><<<nt_blocks, 256, 0, stream>>>(sb0, W1B0, b1_0, tbuf, N);
    bnstats_kernel<<<256, 256, 0, stream>>>(tbuf, sum0, N * 64);
    bnfinal_kernel<<<1, 64, 0, stream>>>(sum0, g0, bb0, scsh0, 1.0f / N);
    ngemm_bn_kernel<<<nt_blocks, 256, 0, stream>>>(
        tbuf, scsh0, W2B0, b2_0, y0, yb, N, 1);

    // ----- layer 1 -----
    edgem_kernel<64><<<edge_blocks, 256, 0, stream>>>(
        yb, ei, eattr, WeB1, be1, inv, pbuf, E);
    gathersum1_kernel<<<n4_blocks, 256, 0, stream>>>(pbuf, offs, y0, sb1, N);
    ngemm_kernel<64><<<nt_blocks, 256, 0, stream>>>(sb1, W1B1, b1_1, tbuf, N);
    bnstats_kernel<<<256, 256, 0, stream>>>(tbuf, sum1, N * 64);
    bnfinal_kernel<<<1, 64, 0, stream>>>(sum1, g1, bb1, scsh1, 1.0f / N);
    ngemm_bn_kernel<<<nt_blocks, 256, 0, stream>>>(
        tbuf, scsh1, W2B1, b2_1, out, yb, N, 0);
}

// Round 11
// 530.884 us; speedup vs baseline: 1.2187x; 1.2187x over previous
//
#include <hip/hip_runtime.h>
#include <hip/hip_bf16.h>

// ---------------------------------------------------------------------------
// GINE 2-layer GNN, MI355X (gfx950)  — round 11
// R10 post-mortem: edge kernel is TRANSACTION-bound: every VMEM instr in
// the 16-edge MFMA layout scatters over 16 rows (~600 segments/wave), and
// 8B/lane scattered stores caused 1.6x HBM write amplification.
// Fix: keep swapped-operand MFMA; stage eattr + x[src] rows through small
// per-wave LDS tiles with 16B/lane ROW-CONTIGUOUS global patterns:
//   eattr: 4 coalesced loads (contiguous 4KB) -> bf16 tile -> ds_read B-frags
//   x:     4 instrs x 4 full rows (256B contiguous each) -> xm tile
//   epilogue: in-place x->m in xm tile (per-lane slot)
//   store: 4 instrs x 4 COMPLETE rows to sorted pbuf positions (full lines)
// No __syncthreads (intra-wave LDS only), lgkmcnt fences between phases.
// ---------------------------------------------------------------------------

typedef short bhalf4 __attribute__((ext_vector_type(4)));
typedef short short8 __attribute__((ext_vector_type(8)));
typedef float f32x4 __attribute__((ext_vector_type(4)));
typedef float f32x2 __attribute__((ext_vector_type(2)));

__device__ __forceinline__ short f2bf(float x) {
    unsigned u = __float_as_uint(x);
    unsigned r = (u + 0x7fffu + ((u >> 16) & 1u)) >> 16;   // RTNE
    return (short)r;
}
__device__ __forceinline__ float bf2f(unsigned short u) {
    return __uint_as_float(((unsigned)u) << 16);
}

// ---------------------------------------------------------------------------
// Counting sort of edges by dst -> inv (edge id -> sorted pos), offs (CSR)
// ---------------------------------------------------------------------------
__global__ __launch_bounds__(256) void hist_kernel(
    const int* __restrict__ ei, int* __restrict__ cnt, int E)
{
    int e = blockIdx.x * 256 + threadIdx.x;
    if (e < E) atomicAdd(&cnt[ei[E + e]], 1);
}

__global__ __launch_bounds__(1024) void scan_kernel(
    const int* __restrict__ cnt, int* __restrict__ offs,
    int* __restrict__ cursor, int N)
{
    __shared__ int wsum[16];
    __shared__ int chunk_base;
    int tid = threadIdx.x;
    int lane = tid & 63, wid = tid >> 6;
    if (tid == 0) chunk_base = 0;
    __syncthreads();
    for (int start = 0; start < N; start += 1024) {
        int i = start + tid;
        int v = (i < N) ? cnt[i] : 0;
        int s = v;
#pragma unroll
        for (int d = 1; d < 64; d <<= 1) {
            int t = __shfl_up(s, d);
            if (lane >= d) s += t;
        }
        if (lane == 63) wsum[wid] = s;
        __syncthreads();
        int wbase = 0;
        for (int w = 0; w < wid; ++w) wbase += wsum[w];
        int excl = chunk_base + wbase + s - v;
        if (i < N) { offs[i] = excl; cursor[i] = excl; }
        int tot = 0;
        for (int w = 0; w < 16; ++w) tot += wsum[w];
        __syncthreads();
        if (tid == 0) chunk_base += tot;
        __syncthreads();
    }
    if (threadIdx.x == 0) offs[N] = chunk_base;
}

__global__ __launch_bounds__(256) void scatter_kernel(
    const int* __restrict__ ei, int* __restrict__ cursor,
    int* __restrict__ inv, int E)
{
    int e = blockIdx.x * 256 + threadIdx.x;
    if (e >= E) return;
    int d = ei[E + e];
    int pos = atomicAdd(&cursor[d], 1);
    inv[e] = pos;
}

// ---------------------------------------------------------------------------
// x -> bf16 cast (grid-stride)
// ---------------------------------------------------------------------------
__global__ __launch_bounds__(256) void xcast_kernel(
    const float* __restrict__ x, unsigned short* __restrict__ xb, int total)
{
    for (int i = blockIdx.x * 256 + threadIdx.x; i < total; i += gridDim.x * 256)
        xb[i] = (unsigned short)f2bf(x[i]);
}

// ---------------------------------------------------------------------------
// Edge kernel (swapped-operand MFMA + LDS-staged coalesced I/O).
//   m[e][f] = relu( (eattr @ We^T)[e][f] + be[f] + x[src(e)][f] )
// Wave = 16 edges. Stores full rows at dst-sorted positions.
// ---------------------------------------------------------------------------
template<int DF>
__global__ __launch_bounds__(256) void edgem_kernel(
    const unsigned short* __restrict__ xb,   // [N][DF] bf16 node feats
    const int*    __restrict__ ei,           // [2][E] (src used)
    const float*  __restrict__ eattr,        // [E][64]
    const short*  __restrict__ WB,           // [DF][64] bf16 (We native)
    const float*  __restrict__ be,           // [DF]
    const int*    __restrict__ inv,          // [E] edge -> sorted pos
    unsigned short* __restrict__ pbuf,       // [E][DF] bf16 (sorted rows)
    int E)
{
    constexpr int FC  = DF / 16;
    constexpr int SA  = 72;        // attr tile row stride (bf16)
    constexpr int SX  = DF + 8;    // xm tile row stride (bf16)
    constexpr int LPR = DF / 8;    // lanes per row at 16B/lane
    constexpr int RPI = 64 / LPR;  // rows per instruction
    constexpr int NI  = 16 / RPI;  // instructions for 16 rows
    __shared__ short attr[4][16][SA];
    __shared__ short xm[4][16][SX];
    const int wave = threadIdx.x >> 6;
    const int lane = threadIdx.x & 63;
    const int ebase = (blockIdx.x * 4 + wave) * 16;
    if (ebase >= E) return;
    const int g = lane >> 4, c = lane & 15;
    short* at = &attr[wave][0][0];
    short* xt = &xm[wave][0][0];

    // ---- stage eattr: 4 coalesced 16B/lane loads of 16 contiguous rows ----
    {
        int r = lane >> 2, q = lane & 3;
        int e = ebase + r;
        const float* src = eattr + (size_t)((e < E) ? e : (E - 1)) * 64;
#pragma unroll
        for (int i = 0; i < 4; ++i) {
            f32x4 v = *(const f32x4*)(src + q * 4 + i * 16);
            bhalf4 b;
            b[0] = f2bf(v[0]); b[1] = f2bf(v[1]); b[2] = f2bf(v[2]); b[3] = f2bf(v[3]);
            *(bhalf4*)(at + r * SA + i * 16 + q * 4) = b;
        }
    }
    // ---- stage x[src] rows: row-contiguous 16B/lane gather ----
    {
#pragma unroll
        for (int i = 0; i < NI; ++i) {
            int r = i * RPI + lane / LPR;
            int q = lane % LPR;
            int e = ebase + r;
            int se = ei[(e < E) ? e : (E - 1)];
            short8 v = *(const short8*)(xb + (size_t)se * DF + q * 8);
            *(short8*)(xt + r * SX + q * 8) = v;
        }
    }
    asm volatile("s_waitcnt lgkmcnt(0)" ::: "memory");
    __builtin_amdgcn_sched_barrier(0);

    // ---- B-frags from attr tile ----
    short8 bfr0 = *(const short8*)(at + c * SA + g * 8);
    short8 bfr1 = *(const short8*)(at + c * SA + 32 + g * 8);

    // ---- FC chunks: 2 MFMA + epilogue (x from LDS, m back in-place) ----
#pragma unroll
    for (int fc = 0; fc < FC; ++fc) {
        const short* aw = WB + (size_t)(fc * 16 + c) * 64 + g * 8;
        short8 aw0 = *(const short8*)(aw);
        short8 aw1 = *(const short8*)(aw + 32);
        f32x4 acc = {0.f, 0.f, 0.f, 0.f};
        acc = __builtin_amdgcn_mfma_f32_16x16x32_bf16(aw0, bfr0, acc, 0, 0, 0);
        acc = __builtin_amdgcn_mfma_f32_16x16x32_bf16(aw1, bfr1, acc, 0, 0, 0);

        f32x4 bev = *(const f32x4*)(be + fc * 16 + g * 4);
        short* slot = xt + c * SX + fc * 16 + g * 4;
        bhalf4 xv = *(const bhalf4*)(slot);
        bhalf4 mo;
#pragma unroll
        for (int r = 0; r < 4; ++r) {
            float v = acc[r] + bev[r] + bf2f((unsigned short)xv[r]);
            mo[r] = f2bf(fmaxf(v, 0.f));
        }
        *(bhalf4*)(slot) = mo;
    }
    asm volatile("s_waitcnt lgkmcnt(0)" ::: "memory");
    __builtin_amdgcn_sched_barrier(0);

    // ---- store: full rows (row-contiguous 16B/lane) at sorted positions ----
    {
#pragma unroll
        for (int i = 0; i < NI; ++i) {
            int r = i * RPI + lane / LPR;
            int q = lane % LPR;
            int e = ebase + r;
            short8 v = *(const short8*)(xt + r * SX + q * 8);
            if (e < E) {
                int sp = inv[e];
                *(short8*)(pbuf + (size_t)sp * DF + q * 8) = v;
            }
        }
    }
}

// ---------------------------------------------------------------------------
// L0 gather-sum (streaming, DF=128): sb[n][k] = bf16(x[n][k] + sum_i pbuf[i][k])
// ---------------------------------------------------------------------------
__global__ __launch_bounds__(256) void gathersum0_kernel(
    const unsigned short* __restrict__ pbuf,   // [E][128] sorted rows
    const int* __restrict__ offs,
    const float* __restrict__ x,               // [N][128] f32
    unsigned short* __restrict__ sb, int N)
{
    int wid = threadIdx.x >> 6, lane = threadIdx.x & 63;
    int n = blockIdx.x * 4 + wid;
    if (n >= N) return;
    f32x2 xx = *(const f32x2*)(x + (size_t)n * 128 + 2 * lane);
    float s0 = xx[0], s1 = xx[1];
    int i0 = offs[n], i1 = offs[n + 1];
    const unsigned int* p = (const unsigned int*)(pbuf + (size_t)i0 * 128) + lane;
    int cnt = i1 - i0;
    int i = 0;
    for (; i + 3 < cnt; i += 4) {
        unsigned int v0 = p[0], v1 = p[64], v2 = p[128], v3 = p[192];
        s0 += bf2f((unsigned short)v0) + bf2f((unsigned short)v1)
            + bf2f((unsigned short)v2) + bf2f((unsigned short)v3);
        s1 += bf2f((unsigned short)(v0 >> 16)) + bf2f((unsigned short)(v1 >> 16))
            + bf2f((unsigned short)(v2 >> 16)) + bf2f((unsigned short)(v3 >> 16));
        p += 256;
    }
    for (; i < cnt; ++i) {
        unsigned int v = p[0];
        s0 += bf2f((unsigned short)v);
        s1 += bf2f((unsigned short)(v >> 16));
        p += 64;
    }
    unsigned int packed = (unsigned int)(unsigned short)f2bf(s0)
                        | ((unsigned int)(unsigned short)f2bf(s1) << 16);
    *(unsigned int*)(sb + (size_t)n * 128 + 2 * lane) = packed;
}

// ---------------------------------------------------------------------------
// L1 gather-sum (streaming, DF=64): sb[n][k] = bf16(y0[n][k] + sum_i pbuf[i][k])
// ---------------------------------------------------------------------------
__global__ __launch_bounds__(256) void gathersum1_kernel(
    const unsigned short* __restrict__ pbuf,   // [E][64] sorted rows
    const int* __restrict__ offs,
    const float* __restrict__ y0, unsigned short* __restrict__ sb, int N)
{
    int wid = threadIdx.x >> 6, lane = threadIdx.x & 63;
    int n = blockIdx.x * 4 + wid;
    if (n >= N) return;
    float s = y0[(size_t)n * 64 + lane];
    int i0 = offs[n], i1 = offs[n + 1];
    const unsigned short* p = pbuf + (size_t)i0 * 64 + lane;
    int cnt = i1 - i0;
    int i = 0;
    for (; i + 3 < cnt; i += 4) {
        s += bf2f(p[0]) + bf2f(p[64]) + bf2f(p[128]) + bf2f(p[192]);
        p += 256;
    }
    for (; i < cnt; ++i) { s += bf2f(p[0]); p += 64; }
    sb[(size_t)n * 64 + lane] = (unsigned short)f2bf(s);
}

// ---------------------------------------------------------------------------
// Node-tile MFMA GEMM: out[n][f] = b[f] + sum_k A[n][k] * W[f][k]
// ---------------------------------------------------------------------------
template<int DIN>
__global__ __launch_bounds__(256) void ngemm_kernel(
    const unsigned short* __restrict__ A,
    const short* __restrict__ W, const float* __restrict__ b,
    float* __restrict__ out, int N)
{
    constexpr int KK = DIN / 32;
    const int wave = threadIdx.x >> 6;
    const int lane = threadIdx.x & 63;
    const int nbase = (blockIdx.x * 4 + wave) * 16;
    if (nbase >= N) return;
    const int g = lane >> 4, c = lane & 15;

    int rowc = nbase + c; if (rowc >= N) rowc = N - 1;
    const unsigned short* arow = A + (size_t)rowc * DIN + g * 8;
    short8 afr[KK];
#pragma unroll
    for (int kk = 0; kk < KK; ++kk)
        afr[kk] = *(const short8*)(arow + kk * 32);

#pragma unroll
    for (int cc = 0; cc < 4; ++cc) {
        const float bev = b[cc * 16 + c];
        f32x4 acc = {bev, bev, bev, bev};
#pragma unroll
        for (int kk = 0; kk < KK; ++kk) {
            short8 bw = *(const short8*)(W + (size_t)(cc * 16 + c) * DIN + kk * 32 + g * 8);
            acc = __builtin_amdgcn_mfma_f32_16x16x32_bf16(afr[kk], bw, acc, 0, 0, 0);
        }
#pragma unroll
        for (int r = 0; r < 4; ++r) {
            int row = nbase + g * 4 + r;
            if (row < N) out[(size_t)row * 64 + cc * 16 + c] = acc[r];
        }
    }
}

// ---------------------------------------------------------------------------
// Node-tile MFMA GEMM with fused BN+relu on the A side
// ---------------------------------------------------------------------------
__global__ __launch_bounds__(256) void ngemm_bn_kernel(
    const float* __restrict__ t, const float* __restrict__ scsh,
    const short* __restrict__ W2, const float* __restrict__ b2,
    float* __restrict__ out, unsigned short* __restrict__ outb,
    int N, int relu_out)
{
    const int wave = threadIdx.x >> 6;
    const int lane = threadIdx.x & 63;
    const int nbase = (blockIdx.x * 4 + wave) * 16;
    if (nbase >= N) return;
    const int g = lane >> 4, c = lane & 15;

    int rowc = nbase + c; if (rowc >= N) rowc = N - 1;
    const float* trow = t + (size_t)rowc * 64 + g * 8;

    short8 afr[2];
#pragma unroll
    for (int kk = 0; kk < 2; ++kk) {
        f32x4 q0 = *(const f32x4*)(trow + kk * 32);
        f32x4 q1 = *(const f32x4*)(trow + kk * 32 + 4);
        const int kbase = kk * 32 + g * 8;
        f32x4 sc0 = *(const f32x4*)(scsh + kbase);
        f32x4 sc1 = *(const f32x4*)(scsh + kbase + 4);
        f32x4 sh0 = *(const f32x4*)(scsh + 64 + kbase);
        f32x4 sh1 = *(const f32x4*)(scsh + 64 + kbase + 4);
#pragma unroll
        for (int j = 0; j < 4; ++j) {
            afr[kk][j]     = f2bf(fmaxf(q0[j] * sc0[j] + sh0[j], 0.f));
            afr[kk][j + 4] = f2bf(fmaxf(q1[j] * sc1[j] + sh1[j], 0.f));
        }
    }

#pragma unroll
    for (int cc = 0; cc < 4; ++cc) {
        const float bev = b2[cc * 16 + c];
        f32x4 acc = {bev, bev, bev, bev};
#pragma unroll
        for (int kk = 0; kk < 2; ++kk) {
            short8 bw = *(const short8*)(W2 + (size_t)(cc * 16 + c) * 64 + kk * 32 + g * 8);
            acc = __builtin_amdgcn_mfma_f32_16x16x32_bf16(afr[kk], bw, acc, 0, 0, 0);
        }
#pragma unroll
        for (int r = 0; r < 4; ++r) {
            int row = nbase + g * 4 + r;
            if (row < N) {
                float v = acc[r];
                if (relu_out) {
                    v = fmaxf(v, 0.f);
                    outb[(size_t)row * 64 + cc * 16 + c] = (unsigned short)f2bf(v);
                }
                out[(size_t)row * 64 + cc * 16 + c] = v;
            }
        }
    }
}

// ---------------------------------------------------------------------------
// BN stats + final
// ---------------------------------------------------------------------------
__global__ __launch_bounds__(256) void bnstats_kernel(
    const float* __restrict__ t, float* __restrict__ sums, int total)
{
    int tid = threadIdx.x;
    float s = 0.f, s2 = 0.f;
    for (int i = blockIdx.x * 256 + tid; i < total; i += gridDim.x * 256) {
        float v = t[i];
        s += v; s2 += v * v;
    }
    __shared__ float ls[256], ls2[256];
    ls[tid] = s; ls2[tid] = s2;
    __syncthreads();
    if (tid < 64) {
        s  = ls[tid]  + ls[tid + 64]  + ls[tid + 128]  + ls[tid + 192];
        s2 = ls2[tid] + ls2[tid + 64] + ls2[tid + 128] + ls2[tid + 192];
        atomicAdd(&sums[tid], s);
        atomicAdd(&sums[64 + tid], s2);
    }
}

__global__ void bnfinal_kernel(const float* __restrict__ sums,
                               const float* __restrict__ g,
                               const float* __restrict__ bb,
                               float* __restrict__ scsh, float invN)
{
    int f = threadIdx.x;  // 64 threads
    float mean = sums[f] * invN;
    float var  = sums[64 + f] * invN - mean * mean;
    float sc = g[f] * rsqrtf(var + 1e-5f);
    scsh[f] = sc;
    scsh[64 + f] = bb[f] - mean * sc;
}

// ---------------------------------------------------------------------------
// Weight prep: f32 -> bf16
// ---------------------------------------------------------------------------
__global__ __launch_bounds__(256) void prep_kernel(
    const float* __restrict__ We0, const float* __restrict__ W1_0,
    const float* __restrict__ We1, const float* __restrict__ W1_1,
    const float* __restrict__ W2_0, const float* __restrict__ W2_1,
    short* __restrict__ WeB0, short* __restrict__ W1B0,
    short* __restrict__ WeB1, short* __restrict__ W1B1,
    short* __restrict__ W2B0, short* __restrict__ W2B1)
{
    int i = blockIdx.x * 256 + threadIdx.x;
    if (i < 128 * 64) WeB0[i] = f2bf(We0[i]);
    if (i < 64 * 128) W1B0[i] = f2bf(W1_0[i]);
    if (i < 64 * 64) {
        WeB1[i] = f2bf(We1[i]);
        W1B1[i] = f2bf(W1_1[i]);
        W2B0[i] = f2bf(W2_0[i]);
        W2B1[i] = f2bf(W2_1[i]);
    }
}

extern "C" void kernel_launch(void* const* d_in, const int* in_sizes, int n_in,
                              void* d_out, int out_size, void* d_ws, size_t ws_size,
                              hipStream_t stream)
{
    (void)n_in; (void)out_size; (void)ws_size;
    const float* x     = (const float*)d_in[0];
    const int*   ei    = (const int*)d_in[1];
    const float* eattr = (const float*)d_in[2];
    const float* We0   = (const float*)d_in[3];
    const float* be0   = (const float*)d_in[4];
    const float* W1_0  = (const float*)d_in[5];
    const float* b1_0  = (const float*)d_in[6];
    const float* g0    = (const float*)d_in[7];
    const float* bb0   = (const float*)d_in[8];
    const float* W2_0  = (const float*)d_in[9];
    const float* b2_0  = (const float*)d_in[10];
    const float* We1   = (const float*)d_in[11];
    const float* be1   = (const float*)d_in[12];
    const float* W1_1  = (const float*)d_in[13];
    const float* b1_1  = (const float*)d_in[14];
    const float* g1    = (const float*)d_in[15];
    const float* bb1   = (const float*)d_in[16];
    const float* W2_1  = (const float*)d_in[17];
    const float* b2_1  = (const float*)d_in[18];
    float* out = (float*)d_out;

    const int N = in_sizes[0] / 128;   // 50000
    const int E = in_sizes[2] / 64;    // 800000

    char* ws = (char*)d_ws;
    size_t o = 0;
    auto alloc = [&](size_t bytes) { char* p = ws + o; o = (o + bytes + 255) & ~(size_t)255; return p; };
    unsigned short* pbuf = (unsigned short*)alloc((size_t)E * 128 * 2);  // L0: [E][128]; L1 reuses as [E][64]
    float* tbuf   = (float*)alloc((size_t)N * 64 * 4);
    float* y0     = (float*)alloc((size_t)N * 64 * 4);
    unsigned short* xb = (unsigned short*)alloc((size_t)N * 128 * 2);   // also sb0 (after edge2)
    unsigned short* yb = (unsigned short*)alloc((size_t)N * 64 * 2);    // also sb1 (after edge1)
    short* WeB0   = (short*)alloc(128 * 64 * 2);
    short* W1B0   = (short*)alloc(64 * 128 * 2);
    short* WeB1   = (short*)alloc(64 * 64 * 2);
    short* W1B1   = (short*)alloc(64 * 64 * 2);
    short* W2B0   = (short*)alloc(64 * 64 * 2);
    short* W2B1   = (short*)alloc(64 * 64 * 2);
    float* stats  = (float*)alloc(512 * 4);
    int*   cnt    = (int*)alloc((size_t)N * 4);
    int*   offs   = (int*)alloc((size_t)(N + 1) * 4);
    int*   inv    = (int*)alloc((size_t)E * 4);
    float* sum0  = stats;
    float* scsh0 = stats + 128;
    float* sum1  = stats + 256;
    float* scsh1 = stats + 384;
    unsigned short* sb0 = xb;   // alias: written after edgem<128> consumed xb
    unsigned short* sb1 = yb;   // alias: written after edgem<64> consumed yb

    (void)hipMemsetAsync(stats, 0, 512 * 4, stream);
    (void)hipMemsetAsync(cnt, 0, (size_t)N * 4, stream);
    prep_kernel<<<64, 256, 0, stream>>>(We0, W1_0, We1, W1_1, W2_0, W2_1,
                                        WeB0, W1B0, WeB1, W1B1, W2B0, W2B1);
    xcast_kernel<<<2048, 256, 0, stream>>>(x, xb, N * 128);

    const int eb256 = (E + 255) / 256;

    // ----- CSR by dst (offs) + edge -> sorted-position map (inv) -----
    hist_kernel<<<eb256, 256, 0, stream>>>(ei, cnt, E);
    scan_kernel<<<1, 1024, 0, stream>>>(cnt, offs, cnt, N);
    scatter_kernel<<<eb256, 256, 0, stream>>>(ei, cnt, inv, E);

    const int edge_blocks = ((E + 15) / 16 + 3) / 4;
    const int n4_blocks   = (N + 3) / 4;
    const int nt_blocks   = ((N + 15) / 16 + 3) / 4;

    // ----- layer 0 -----
    edgem_kernel<128><<<edge_blocks, 256, 0, stream>>>(
        xb, ei, eattr, WeB0, be0, inv, pbuf, E);
    gathersum0_kernel<<<n4_blocks, 256, 0, stream>>>(pbuf, offs, x, sb0, N);
    ngemm_kernel<128><<<nt_blocks, 256, 0, stream>>>(sb0, W1B0, b1_0, tbuf, N);
    bnstats_kernel<<<256, 256, 0, stream>>>(tbuf, sum0, N * 64);
    bnfinal_kernel<<<1, 64, 0, stream>>>(sum0, g0, bb0, scsh0, 1.0f / N);
    ngemm_bn_kernel<<<nt_blocks, 256, 0, stream>>>(
        tbuf, scsh0, W2B0, b2_0, y0, yb, N, 1);

    // ----- layer 1 -----
    edgem_kernel<64><<<edge_blocks, 256, 0, stream>>>(
        yb, ei, eattr, WeB1, be1, inv, pbuf, E);
    gathersum1_kernel<<<n4_blocks, 256, 0, stream>>>(pbuf, offs, y0, sb1, N);
    ngemm_kernel<64><<<nt_blocks, 256, 0, stream>>>(sb1, W1B1, b1_1, tbuf, N);
    bnstats_kernel<<<256, 256, 0, stream>>>(tbuf, sum1, N * 64);
    bnfinal_kernel<<<1, 64, 0, stream>>>(sum1, g1, bb1, scsh1, 1.0f / N);
    ngemm_bn_kernel<<<nt_blocks, 256, 0, stream>>>(
        tbuf, scsh1, W2B1, b2_1, out, yb, N, 0);
}